// Round 1
// baseline (2047.658 us; speedup 1.0000x reference)
//
#include <hip/hip_runtime.h>
#include <math.h>

#define NB 64
#define NP 16320
#define NO 24
#define NC 81

// ---------------------------------------------------------------------------
// Workspace layout (bytes):
//   [0,           12288)   best_key  : u64[NB*NO]   (zeroed each launch)
//   [12288,       12544)   npos      : int[NB]      (zeroed)
//   [12544,       12560)   acc       : float[4]     (zeroed) 0=loss_l 1=ce_pos 2=ce_neg
//   [12800,       ...  )   bto       : float[NB*NP]
//   next                   bti       : int  [NB*NP]
//   next                   ce_mine   : float[NB*NP]
// Total = 12800 + 3*NB*NP*4 = 12,546,560 bytes
// ---------------------------------------------------------------------------

__device__ __forceinline__ float smooth_l1(float d) {
    float a = fabsf(d);
    return (a < 1.0f) ? 0.5f * a * a : a - 0.5f;
}

// Kernel 1: decode ARM boxes, IoU vs truths, per-prior best (bto/bti),
// per-truth best prior via packed (iou_bits<<32 | ~p) atomicMax (ties -> smallest p).
__global__ __launch_bounds__(256) void k_match(
    const float* __restrict__ arm_loc, const float* __restrict__ priors,
    const float* __restrict__ gt_boxes,
    float* __restrict__ bto, int* __restrict__ bti,
    unsigned long long* __restrict__ best_key)
{
    const int b   = blockIdx.y;
    const int p   = blockIdx.x * 256 + threadIdx.x;
    const int tid = threadIdx.x;

    __shared__ float tr[NO * 4];
    __shared__ unsigned long long sh_best[NO];
    if (tid < NO * 4) tr[tid] = gt_boxes[b * NO * 4 + tid];
    if (tid < NO)     sh_best[tid] = 0ULL;
    __syncthreads();

    if (p < NP) {
        const size_t idx = (size_t)b * NP + p;
        const float l0 = arm_loc[idx * 4 + 0];
        const float l1 = arm_loc[idx * 4 + 1];
        const float l2 = arm_loc[idx * 4 + 2];
        const float l3 = arm_loc[idx * 4 + 3];
        const float pcx = priors[p * 4 + 0], pcy = priors[p * 4 + 1];
        const float pwx = priors[p * 4 + 2], pwy = priors[p * 4 + 3];
        // decode (match reference FP order)
        const float cx = pcx + l0 * 0.1f * pwx;
        const float cy = pcy + l1 * 0.1f * pwy;
        const float wx = pwx * expf(l2 * 0.2f);
        const float wy = pwy * expf(l3 * 0.2f);
        const float x0 = cx - wx * 0.5f, y0 = cy - wy * 0.5f;
        const float x1 = cx + wx * 0.5f, y1 = cy + wy * 0.5f;
        const float area_b = (x1 - x0) * (y1 - y0);

        float best = -1.0f;
        int   besto = 0;
        const unsigned long long lowkey = (unsigned long long)(~(unsigned)p);
        for (int o = 0; o < NO; ++o) {
            const float tx0 = tr[o * 4 + 0], ty0 = tr[o * 4 + 1];
            const float tx1 = tr[o * 4 + 2], ty1 = tr[o * 4 + 3];
            const float area_a = (tx1 - tx0) * (ty1 - ty0);
            const float ix0 = fmaxf(tx0, x0), iy0 = fmaxf(ty0, y0);
            const float ix1 = fminf(tx1, x1), iy1 = fminf(ty1, y1);
            const float iw = fmaxf(ix1 - ix0, 0.0f);
            const float ih = fmaxf(iy1 - iy0, 0.0f);
            const float inter = iw * ih;
            const float iou = inter / (area_a + area_b - inter);
            if (iou > best) { best = iou; besto = o; }  // first occurrence on ties
            const unsigned long long key =
                ((unsigned long long)__float_as_uint(iou) << 32) | lowkey;
            atomicMax(&sh_best[o], key);
        }
        bto[idx] = best;
        bti[idx] = besto;
    }
    __syncthreads();
    if (tid < NO) atomicMax(&best_key[b * NO + tid], sh_best[tid]);
}

// Kernel 2: force-match best prior per truth, sequential per-b (last write wins,
// matching np scatter semantics on duplicate indices).
__global__ void k_force(const unsigned long long* __restrict__ best_key,
                        float* __restrict__ bto, int* __restrict__ bti)
{
    const int b = blockIdx.x * blockDim.x + threadIdx.x;
    if (b >= NB) return;
    for (int o = 0; o < NO; ++o) {
        const unsigned long long k = best_key[b * NO + o];
        const unsigned p = ~(unsigned)(k & 0xffffffffULL);
        bto[(size_t)b * NP + p] = 2.0f;
        bti[(size_t)b * NP + p] = o;
    }
}

// Kernel 3: per-prior conf_t / pos gate / SmoothL1 (positives) / CE via
// single-pass online logsumexp. Writes ce_mine; accumulates loss_l, pos-CE, npos.
__global__ __launch_bounds__(256) void k_loss(
    const float* __restrict__ arm_loc, const float* __restrict__ arm_conf,
    const float* __restrict__ odm_loc, const float* __restrict__ odm_conf,
    const float* __restrict__ priors,  const float* __restrict__ gt_boxes,
    const int*   __restrict__ gt_labels,
    const float* __restrict__ bto, const int* __restrict__ bti,
    float* __restrict__ ce_mine, int* __restrict__ npos, float* __restrict__ acc)
{
    const int b   = blockIdx.y;
    const int p   = blockIdx.x * 256 + threadIdx.x;
    const int tid = threadIdx.x;

    float local_l = 0.0f, local_ce = 0.0f;
    int   local_n = 0;

    if (p < NP) {
        const size_t idx = (size_t)b * NP + p;
        const float ov = bto[idx];
        const int   ti = bti[idx];
        int conf_t = 0;
        if (!(ov < 0.5f)) conf_t = gt_labels[b * NO + ti];

        // ARM objectness score = softmax(arm_conf)[1]
        const float c0 = arm_conf[idx * 2 + 0];
        const float c1 = arm_conf[idx * 2 + 1];
        const float mm = fmaxf(c0, c1);
        const float e0 = expf(c0 - mm), e1 = expf(c1 - mm);
        const float score = e1 / (e0 + e1);
        const bool pos = (conf_t > 0) && (score > 0.01f);

        // CE = logsumexp(row) - row[conf_t], online single-pass
        const float* row = odm_conf + idx * NC;
        float mx = row[0];
        float s  = 1.0f;
        float g  = row[0];
        for (int i = 1; i < NC; ++i) {
            const float x = row[i];
            if (i == conf_t) g = x;
            if (x > mx) { s = s * expf(mx - x) + 1.0f; mx = x; }
            else        { s += expf(x - mx); }
        }
        const float ce = (mx + logf(s)) - g;

        float cem = ce;
        if (pos) {
            cem      = 0.0f;
            local_ce = ce;
            local_n  = 1;
            // re-decode ARM box (same FP path as k_match)
            const float l0 = arm_loc[idx * 4 + 0];
            const float l1 = arm_loc[idx * 4 + 1];
            const float l2 = arm_loc[idx * 4 + 2];
            const float l3 = arm_loc[idx * 4 + 3];
            const float pcx = priors[p * 4 + 0], pcy = priors[p * 4 + 1];
            const float pwx = priors[p * 4 + 2], pwy = priors[p * 4 + 3];
            const float cx = pcx + l0 * 0.1f * pwx;
            const float cy = pcy + l1 * 0.1f * pwy;
            const float wx = pwx * expf(l2 * 0.2f);
            const float wy = pwy * expf(l3 * 0.2f);
            const float x0 = cx - wx * 0.5f, y0 = cy - wy * 0.5f;
            const float x1 = cx + wx * 0.5f, y1 = cy + wy * 0.5f;
            // center-size of decoded box
            const float csx = (x0 + x1) * 0.5f, csy = (y0 + y1) * 0.5f;
            const float csw = x1 - x0,          csh = y1 - y0;
            // encode matched truth
            const float m0 = gt_boxes[(b * NO + ti) * 4 + 0];
            const float m1 = gt_boxes[(b * NO + ti) * 4 + 1];
            const float m2 = gt_boxes[(b * NO + ti) * 4 + 2];
            const float m3 = gt_boxes[(b * NO + ti) * 4 + 3];
            const float t0 = ((m0 + m2) * 0.5f - csx) / (0.1f * csw);
            const float t1 = ((m1 + m3) * 0.5f - csy) / (0.1f * csh);
            const float t2 = logf((m2 - m0) / csw) / 0.2f;
            const float t3 = logf((m3 - m1) / csh) / 0.2f;
            local_l += smooth_l1(odm_loc[idx * 4 + 0] - t0);
            local_l += smooth_l1(odm_loc[idx * 4 + 1] - t1);
            local_l += smooth_l1(odm_loc[idx * 4 + 2] - t2);
            local_l += smooth_l1(odm_loc[idx * 4 + 3] - t3);
        }
        ce_mine[idx] = cem;
    }

    // block reduction
    __shared__ float sl[256];
    __shared__ float sc[256];
    __shared__ int   sn[256];
    sl[tid] = local_l; sc[tid] = local_ce; sn[tid] = local_n;
    __syncthreads();
    for (int st = 128; st > 0; st >>= 1) {
        if (tid < st) {
            sl[tid] += sl[tid + st];
            sc[tid] += sc[tid + st];
            sn[tid] += sn[tid + st];
        }
        __syncthreads();
    }
    if (tid == 0) {
        if (sl[0] != 0.0f) atomicAdd(&acc[0], sl[0]);
        if (sc[0] != 0.0f) atomicAdd(&acc[1], sc[0]);
        if (sn[0] != 0)    atomicAdd(&npos[b], sn[0]);
    }
}

// Kernel 4: per-row radix select of k-th largest ce_mine (k = min(3*npos, P-1)),
// then neg contribution = sum(ce_mine > T) + (k - count(>T)) * T.
// Exact vs argsort-based top-k: tied values contribute identically.
__global__ __launch_bounds__(256) void k_select(
    const float* __restrict__ ce_mine, const int* __restrict__ npos,
    float* __restrict__ acc)
{
    const int b   = blockIdx.x;
    const int tid = threadIdx.x;
    const int np  = npos[b];
    int k = 3 * np;
    if (k > NP - 1) k = NP - 1;
    if (k <= 0) return;

    const float* row = ce_mine + (size_t)b * NP;

    __shared__ unsigned int hist[256];
    __shared__ unsigned int sh_prefix, sh_mask, sh_krem;
    if (tid == 0) { sh_prefix = 0u; sh_mask = 0u; sh_krem = (unsigned)k; }
    __syncthreads();

    for (int pass = 3; pass >= 0; --pass) {
        hist[tid] = 0u;
        __syncthreads();
        const unsigned mask = sh_mask, prefix = sh_prefix;
        const int shift = pass * 8;
        for (int i = tid; i < NP; i += 256) {
            const unsigned u = __float_as_uint(row[i]);   // ce >= 0 -> monotonic bits
            if ((u & mask) == prefix) atomicAdd(&hist[(u >> shift) & 255u], 1u);
        }
        __syncthreads();
        if (tid == 0) {
            unsigned cum = 0, krem = sh_krem;
            for (int bin = 255; bin >= 0; --bin) {
                const unsigned h = hist[bin];
                if (cum + h >= krem) {
                    sh_prefix = prefix | ((unsigned)bin << shift);
                    sh_mask   = mask | (255u << shift);
                    sh_krem   = krem - cum;
                    break;
                }
                cum += h;
            }
        }
        __syncthreads();
    }

    const unsigned T = sh_prefix;   // exact bits of k-th largest
    float    lsum = 0.0f;
    unsigned lcnt = 0;
    for (int i = tid; i < NP; i += 256) {
        const float    v = row[i];
        const unsigned u = __float_as_uint(v);
        if (u > T) { lsum += v; lcnt++; }
    }
    __shared__ float    ssum[256];
    __shared__ unsigned scnt[256];
    ssum[tid] = lsum; scnt[tid] = lcnt;
    __syncthreads();
    for (int st = 128; st > 0; st >>= 1) {
        if (tid < st) { ssum[tid] += ssum[tid + st]; scnt[tid] += scnt[tid + st]; }
        __syncthreads();
    }
    if (tid == 0) {
        const float tf = __uint_as_float(T);
        const float contrib = ssum[0] + (float)(k - (int)scnt[0]) * tf;
        atomicAdd(&acc[2], contrib);
    }
}

// Kernel 5: finalize
__global__ void k_final(const float* __restrict__ acc, const int* __restrict__ npos,
                        float* __restrict__ out)
{
    if (threadIdx.x == 0 && blockIdx.x == 0) {
        int n = 0;
        for (int b = 0; b < NB; ++b) n += npos[b];
        const float N = (float)n;
        out[0] = acc[0] / N;
        out[1] = (acc[1] + acc[2]) / N;
    }
}

extern "C" void kernel_launch(void* const* d_in, const int* in_sizes, int n_in,
                              void* d_out, int out_size, void* d_ws, size_t ws_size,
                              hipStream_t stream)
{
    const float* arm_loc   = (const float*)d_in[0];
    const float* arm_conf  = (const float*)d_in[1];
    const float* odm_loc   = (const float*)d_in[2];
    const float* odm_conf  = (const float*)d_in[3];
    const float* priors    = (const float*)d_in[4];
    const float* gt_boxes  = (const float*)d_in[5];
    const int*   gt_labels = (const int*)d_in[6];
    float* out = (float*)d_out;

    char* ws = (char*)d_ws;
    unsigned long long* best_key = (unsigned long long*)ws;          // 12288 B
    int*   npos = (int*)  (ws + 12288);                              // 256 B
    float* acc  = (float*)(ws + 12544);                              // 16 B
    float* bto  = (float*)(ws + 12800);
    int*   bti  = (int*)  (ws + 12800 + (size_t)NB * NP * 4);
    float* cem  = (float*)(ws + 12800 + 2ULL * NB * NP * 4);

    hipMemsetAsync(d_ws, 0, 12560, stream);

    dim3 grid((NP + 255) / 256, NB);
    k_match <<<grid, 256, 0, stream>>>(arm_loc, priors, gt_boxes, bto, bti, best_key);
    k_force <<<1, 64, 0, stream>>>(best_key, bto, bti);
    k_loss  <<<grid, 256, 0, stream>>>(arm_loc, arm_conf, odm_loc, odm_conf, priors,
                                       gt_boxes, gt_labels, bto, bti, cem, npos, acc);
    k_select<<<NB, 256, 0, stream>>>(cem, npos, acc);
    k_final <<<1, 1, 0, stream>>>(acc, npos, out);
}

// Round 2
// 970.392 us; speedup vs baseline: 2.1101x; 2.1101x over previous
//
#include <hip/hip_runtime.h>
#include <math.h>

#define NB 64
#define NP 16320
#define NO 24
#define NC 81

// ---------------------------------------------------------------------------
// Workspace layout (bytes):
//   [0,           12288)   best_key  : u64[NB*NO]   (zeroed each launch)
//   [12288,       12544)   npos      : int[NB]      (zeroed)
//   [12544,       12560)   acc       : float[4]     (zeroed) 0=loss_l 1=ce_pos 2=ce_neg
//   [12800,       ...  )   bto       : float[NB*NP]
//   next                   bti       : int  [NB*NP]
//   next                   ce_mine   : float[NB*NP]
// ---------------------------------------------------------------------------

__device__ __forceinline__ float smooth_l1(float d) {
    float a = fabsf(d);
    return (a < 1.0f) ? 0.5f * a * a : a - 0.5f;
}

// Kernel 1: decode ARM boxes (float4 loads), IoU vs truths, per-prior best
// (bto/bti), per-truth best prior via wave shuffle-max then 1 atomic/wave.
// Key = (iou_bits<<32 | ~p) so ties pick smallest p (first occurrence).
__global__ __launch_bounds__(256) void k_match(
    const float* __restrict__ arm_loc, const float* __restrict__ priors,
    const float* __restrict__ gt_boxes,
    float* __restrict__ bto, int* __restrict__ bti,
    unsigned long long* __restrict__ best_key)
{
    const int b   = blockIdx.y;
    const int p   = blockIdx.x * 256 + threadIdx.x;
    const int tid = threadIdx.x;
    const bool valid = (p < NP);

    __shared__ float tr[NO * 4];
    __shared__ unsigned long long sh_best[NO];
    if (tid < NO * 4) tr[tid] = gt_boxes[b * NO * 4 + tid];
    if (tid < NO)     sh_best[tid] = 0ULL;
    __syncthreads();

    float x0 = 0, y0 = 0, x1 = 0, y1 = 0, area_b = 0;
    size_t idx = (size_t)b * NP + (valid ? p : 0);
    if (valid) {
        const float4 l  = ((const float4*)arm_loc)[idx];
        const float4 pr = ((const float4*)priors)[p];
        const float cx = pr.x + l.x * 0.1f * pr.z;
        const float cy = pr.y + l.y * 0.1f * pr.w;
        const float wx = pr.z * expf(l.z * 0.2f);
        const float wy = pr.w * expf(l.w * 0.2f);
        x0 = cx - wx * 0.5f; y0 = cy - wy * 0.5f;
        x1 = cx + wx * 0.5f; y1 = cy + wy * 0.5f;
        area_b = (x1 - x0) * (y1 - y0);
    }

    float best = -1.0f;
    int   besto = 0;
    const unsigned lowkey = ~(unsigned)p;

    for (int o = 0; o < NO; ++o) {
        unsigned hi = 0u, lo = 0u;
        if (valid) {
            const float tx0 = tr[o * 4 + 0], ty0 = tr[o * 4 + 1];
            const float tx1 = tr[o * 4 + 2], ty1 = tr[o * 4 + 3];
            const float area_a = (tx1 - tx0) * (ty1 - ty0);
            const float ix0 = fmaxf(tx0, x0), iy0 = fmaxf(ty0, y0);
            const float ix1 = fminf(tx1, x1), iy1 = fminf(ty1, y1);
            const float iw = fmaxf(ix1 - ix0, 0.0f);
            const float ih = fmaxf(iy1 - iy0, 0.0f);
            const float inter = iw * ih;
            const float iou = inter / (area_a + area_b - inter);
            if (iou > best) { best = iou; besto = o; }  // first occurrence on ties
            hi = __float_as_uint(iou);  // iou >= 0 -> monotonic bits
            lo = lowkey;
        }
        // wave-level max of (hi, lo) -- all 64 lanes participate
        for (int d = 1; d < 64; d <<= 1) {
            const unsigned h2 = __shfl_xor(hi, d, 64);
            const unsigned l2 = __shfl_xor(lo, d, 64);
            if (h2 > hi || (h2 == hi && l2 > lo)) { hi = h2; lo = l2; }
        }
        if ((tid & 63) == 0) {
            const unsigned long long key = ((unsigned long long)hi << 32) | lo;
            atomicMax(&sh_best[o], key);
        }
    }

    if (valid) {
        bto[idx] = best;
        bti[idx] = besto;
    }
    __syncthreads();
    if (tid < NO) atomicMax(&best_key[b * NO + tid], sh_best[tid]);
}

// Kernel 2: force-match best prior per truth (last write wins = np scatter).
__global__ void k_force(const unsigned long long* __restrict__ best_key,
                        float* __restrict__ bto, int* __restrict__ bti)
{
    const int b = blockIdx.x * blockDim.x + threadIdx.x;
    if (b >= NB) return;
    for (int o = 0; o < NO; ++o) {
        const unsigned long long k = best_key[b * NO + o];
        const unsigned p = ~(unsigned)(k & 0xffffffffULL);
        bto[(size_t)b * NP + p] = 2.0f;
        bti[(size_t)b * NP + p] = o;
    }
}

// Kernel 3: LDS-staged coalesced CE + SmoothL1.
// Block owns 256 consecutive global rows (over B*P = 1,044,480 = 4080*256).
// 4 phases: stage 64 rows of odm_conf (5184 floats) into LDS via float4
// coalesced loads; 4 threads/row compute partial online-logsumexp over ~21
// elems each; combine via shfl_xor butterfly (groups of 4).
__global__ __launch_bounds__(256) void k_loss(
    const float* __restrict__ arm_loc, const float* __restrict__ arm_conf,
    const float* __restrict__ odm_loc, const float* __restrict__ odm_conf,
    const float* __restrict__ priors,  const float* __restrict__ gt_boxes,
    const int*   __restrict__ gt_labels,
    const float* __restrict__ bto, const int* __restrict__ bti,
    float* __restrict__ ce_mine, int* __restrict__ npos, float* __restrict__ acc)
{
    const int tid = threadIdx.x;
    const size_t rbase = (size_t)blockIdx.x * 256;

    __shared__ float4 stage4[(64 * NC + 3) / 4];       // 5184 floats = 1296 float4
    __shared__ float  ce_sh[256];
    __shared__ int    conf_sh[256];
    float* stage = (float*)stage4;

    // Per-row target class (needed for the gather inside logsumexp).
    {
        const size_t row = rbase + tid;
        const int   bb = (int)(row / NP);
        const float ov = bto[row];
        const int   ti = bti[row];
        int ct = 0;
        if (!(ov < 0.5f)) ct = gt_labels[bb * NO + ti];
        conf_sh[tid] = ct;
    }
    __syncthreads();

    for (int s = 0; s < 4; ++s) {
        // Stage: 64 rows = 1296 float4, contiguous & 16B-aligned
        const float4* src4 = (const float4*)(odm_conf + (rbase + 64 * (size_t)s) * NC);
        for (int i = tid; i < 1296; i += 256) stage4[i] = src4[i];
        __syncthreads();

        const int lr  = tid >> 2;          // local row 0..63
        const int q   = tid & 3;           // quarter 0..3
        const int tgt = conf_sh[64 * s + lr];
        const int j0  = q * 21;
        const int j1  = (q == 3) ? 81 : j0 + 21;
        const float* rowp = stage + lr * NC;

        float m = -INFINITY, sum = 0.0f, g = -INFINITY;
        for (int j = j0; j < j1; ++j) {
            const float x = rowp[j];
            if (j == tgt) g = x;
            if (x > m) { sum = sum * expf(m - x) + 1.0f; m = x; }
            else       { sum += expf(x - m); }
        }
        // combine the 4 partials (butterfly within groups of 4 lanes)
        for (int d = 1; d < 4; d <<= 1) {
            const float m2 = __shfl_xor(m,   d, 64);
            const float s2 = __shfl_xor(sum, d, 64);
            const float g2 = __shfl_xor(g,   d, 64);
            const float M  = fmaxf(m, m2);
            sum = sum * expf(m - M) + s2 * expf(m2 - M);
            m = M;
            g = fmaxf(g, g2);
        }
        if (q == 0) ce_sh[64 * s + lr] = (m + logf(sum)) - g;
        __syncthreads();   // protect stage for next phase / epilogue reuse
    }

    // Epilogue: per-thread row work
    float local_l = 0.0f, local_ce = 0.0f;
    int   local_n = 0;
    {
        const size_t row = rbase + tid;
        const int bb = (int)(row / NP);
        const int p  = (int)(row - (size_t)bb * NP);
        const int ct = conf_sh[tid];
        const float ce = ce_sh[tid];

        const float2 c = ((const float2*)arm_conf)[row];
        const float mm = fmaxf(c.x, c.y);
        const float e0 = expf(c.x - mm), e1 = expf(c.y - mm);
        const float score = e1 / (e0 + e1);
        const bool pos = (ct > 0) && (score > 0.01f);

        float cem = ce;
        if (pos) {
            cem      = 0.0f;
            local_ce = ce;
            local_n  = 1;
            const float4 l  = ((const float4*)arm_loc)[row];
            const float4 pr = ((const float4*)priors)[p];
            const float cx = pr.x + l.x * 0.1f * pr.z;
            const float cy = pr.y + l.y * 0.1f * pr.w;
            const float wx = pr.z * expf(l.z * 0.2f);
            const float wy = pr.w * expf(l.w * 0.2f);
            const float x0 = cx - wx * 0.5f, y0 = cy - wy * 0.5f;
            const float x1 = cx + wx * 0.5f, y1 = cy + wy * 0.5f;
            const float csx = (x0 + x1) * 0.5f, csy = (y0 + y1) * 0.5f;
            const float csw = x1 - x0,          csh = y1 - y0;
            const int ti = bti[row];
            const float4 mt = ((const float4*)gt_boxes)[bb * NO + ti];
            const float t0 = ((mt.x + mt.z) * 0.5f - csx) / (0.1f * csw);
            const float t1 = ((mt.y + mt.w) * 0.5f - csy) / (0.1f * csh);
            const float t2 = logf((mt.z - mt.x) / csw) / 0.2f;
            const float t3 = logf((mt.w - mt.y) / csh) / 0.2f;
            const float4 ol = ((const float4*)odm_loc)[row];
            local_l += smooth_l1(ol.x - t0);
            local_l += smooth_l1(ol.y - t1);
            local_l += smooth_l1(ol.z - t2);
            local_l += smooth_l1(ol.w - t3);
        }
        ce_mine[row] = cem;
    }

    // block reduction (reuse stage LDS; protected by the final phase sync)
    float* sl = stage;
    float* sc = stage + 256;
    int*   sn = (int*)(stage + 512);
    sl[tid] = local_l; sc[tid] = local_ce; sn[tid] = local_n;
    __syncthreads();
    for (int st = 128; st > 0; st >>= 1) {
        if (tid < st) {
            sl[tid] += sl[tid + st];
            sc[tid] += sc[tid + st];
            sn[tid] += sn[tid + st];
        }
        __syncthreads();
    }
    if (tid == 0) {
        const size_t row0 = rbase;               // all rows in block share... may span 2 b's
        if (sl[0] != 0.0f) atomicAdd(&acc[0], sl[0]);
        if (sc[0] != 0.0f) atomicAdd(&acc[1], sc[0]);
        (void)row0;
    }
    // npos must be per-batch: a block can span a batch boundary, so count
    // positives per-batch via wave-level vote instead of the fused reduction.
    // Simple correct fallback: atomic per positive thread into npos[bb].
    {
        const size_t row = rbase + tid;
        const int bb = (int)(row / NP);
        if (local_n) atomicAdd(&npos[bb], 1);
    }
}

// Kernel 4: per-row radix select of k-th largest ce_mine (k = min(3*npos, P-1)),
// neg contribution = sum(ce_mine > T) + (k - count(>T)) * T.  float4 reads.
__global__ __launch_bounds__(256) void k_select(
    const float* __restrict__ ce_mine, const int* __restrict__ npos,
    float* __restrict__ acc)
{
    const int b   = blockIdx.x;
    const int tid = threadIdx.x;
    const int np  = npos[b];
    int k = 3 * np;
    if (k > NP - 1) k = NP - 1;
    if (k <= 0) return;

    const float4* row4 = (const float4*)(ce_mine + (size_t)b * NP);  // 4080 float4

    __shared__ unsigned int hist[256];
    __shared__ unsigned int sh_prefix, sh_mask, sh_krem;
    if (tid == 0) { sh_prefix = 0u; sh_mask = 0u; sh_krem = (unsigned)k; }
    __syncthreads();

    for (int pass = 3; pass >= 0; --pass) {
        hist[tid] = 0u;
        __syncthreads();
        const unsigned mask = sh_mask, prefix = sh_prefix;
        const int shift = pass * 8;
        for (int i = tid; i < 4080; i += 256) {
            const float4 v = row4[i];
            const unsigned u0 = __float_as_uint(v.x);
            const unsigned u1 = __float_as_uint(v.y);
            const unsigned u2 = __float_as_uint(v.z);
            const unsigned u3 = __float_as_uint(v.w);
            if ((u0 & mask) == prefix) atomicAdd(&hist[(u0 >> shift) & 255u], 1u);
            if ((u1 & mask) == prefix) atomicAdd(&hist[(u1 >> shift) & 255u], 1u);
            if ((u2 & mask) == prefix) atomicAdd(&hist[(u2 >> shift) & 255u], 1u);
            if ((u3 & mask) == prefix) atomicAdd(&hist[(u3 >> shift) & 255u], 1u);
        }
        __syncthreads();
        if (tid == 0) {
            unsigned cum = 0, krem = sh_krem;
            for (int bin = 255; bin >= 0; --bin) {
                const unsigned h = hist[bin];
                if (cum + h >= krem) {
                    sh_prefix = prefix | ((unsigned)bin << shift);
                    sh_mask   = mask | (255u << shift);
                    sh_krem   = krem - cum;
                    break;
                }
                cum += h;
            }
        }
        __syncthreads();
    }

    const unsigned T = sh_prefix;   // exact bits of k-th largest
    float    lsum = 0.0f;
    unsigned lcnt = 0;
    for (int i = tid; i < 4080; i += 256) {
        const float4 v = row4[i];
        if (__float_as_uint(v.x) > T) { lsum += v.x; lcnt++; }
        if (__float_as_uint(v.y) > T) { lsum += v.y; lcnt++; }
        if (__float_as_uint(v.z) > T) { lsum += v.z; lcnt++; }
        if (__float_as_uint(v.w) > T) { lsum += v.w; lcnt++; }
    }
    __shared__ float    ssum[256];
    __shared__ unsigned scnt[256];
    ssum[tid] = lsum; scnt[tid] = lcnt;
    __syncthreads();
    for (int st = 128; st > 0; st >>= 1) {
        if (tid < st) { ssum[tid] += ssum[tid + st]; scnt[tid] += scnt[tid + st]; }
        __syncthreads();
    }
    if (tid == 0) {
        const float tf = __uint_as_float(T);
        const float contrib = ssum[0] + (float)(k - (int)scnt[0]) * tf;
        atomicAdd(&acc[2], contrib);
    }
}

// Kernel 5: finalize
__global__ void k_final(const float* __restrict__ acc, const int* __restrict__ npos,
                        float* __restrict__ out)
{
    if (threadIdx.x == 0 && blockIdx.x == 0) {
        int n = 0;
        for (int b = 0; b < NB; ++b) n += npos[b];
        const float N = (float)n;
        out[0] = acc[0] / N;
        out[1] = (acc[1] + acc[2]) / N;
    }
}

extern "C" void kernel_launch(void* const* d_in, const int* in_sizes, int n_in,
                              void* d_out, int out_size, void* d_ws, size_t ws_size,
                              hipStream_t stream)
{
    const float* arm_loc   = (const float*)d_in[0];
    const float* arm_conf  = (const float*)d_in[1];
    const float* odm_loc   = (const float*)d_in[2];
    const float* odm_conf  = (const float*)d_in[3];
    const float* priors    = (const float*)d_in[4];
    const float* gt_boxes  = (const float*)d_in[5];
    const int*   gt_labels = (const int*)d_in[6];
    float* out = (float*)d_out;

    char* ws = (char*)d_ws;
    unsigned long long* best_key = (unsigned long long*)ws;          // 12288 B
    int*   npos = (int*)  (ws + 12288);                              // 256 B
    float* acc  = (float*)(ws + 12544);                              // 16 B
    float* bto  = (float*)(ws + 12800);
    int*   bti  = (int*)  (ws + 12800 + (size_t)NB * NP * 4);
    float* cem  = (float*)(ws + 12800 + 2ULL * NB * NP * 4);

    hipMemsetAsync(d_ws, 0, 12560, stream);

    dim3 grid((NP + 255) / 256, NB);
    k_match <<<grid, 256, 0, stream>>>(arm_loc, priors, gt_boxes, bto, bti, best_key);
    k_force <<<1, 64, 0, stream>>>(best_key, bto, bti);
    k_loss  <<<4080, 256, 0, stream>>>(arm_loc, arm_conf, odm_loc, odm_conf, priors,
                                       gt_boxes, gt_labels, bto, bti, cem, npos, acc);
    k_select<<<NB, 256, 0, stream>>>(cem, npos, acc);
    k_final <<<1, 1, 0, stream>>>(acc, npos, out);
}